// Round 5
// baseline (472.122 us; speedup 1.0000x reference)
//
#include <hip/hip_runtime.h>
#include <cstdint>

// Problem dims (compile-time)
#define B_DIM 8192
#define IN_DIM 1024
#define H_DIM 2048
#define KC 3072      // IN + H (both GEMMs have K = 3072)
#define NTILES 48    // KC / 64
#define LASTT 47
// Stage source offsets for (half h, round q): (h*128 + q*64) * KC elems
#define OFF_H0Q0 0
#define OFF_H0Q1 196608
#define OFF_H1Q0 393216
#define OFF_H1Q1 589824

typedef __attribute__((ext_vector_type(8))) __bf16 bf16x8;
typedef __attribute__((ext_vector_type(4))) float f32x4;

// ---------- helpers ----------
__device__ __forceinline__ unsigned short f2bf(float f) {
  unsigned int u = __float_as_uint(f);
  unsigned int r = (u + 0x7fffu + ((u >> 16) & 1u)) >> 16;
  return (unsigned short)r;
}
__device__ __forceinline__ float sigmoidf_(float x) {
  return 1.0f / (1.0f + __expf(-x));
}
__device__ __forceinline__ float tanhf_(float x) {
  float xc = fminf(fmaxf(x, -15.f), 15.f);
  float t = __expf(2.f * xc);
  return (t - 1.f) / (t + 1.f);
}
__device__ __forceinline__ void gload16(const unsigned short* g, unsigned short* l) {
  __builtin_amdgcn_global_load_lds(
      (const __attribute__((address_space(1))) unsigned int*)(g),
      (__attribute__((address_space(3))) unsigned int*)(l),
      16, 0, 0);
}

// ---------- fused pack: all fp32->bf16 conversions in one launch ----------
__device__ __forceinline__ void cvt4(const float* s, unsigned short* d) {
  const float4 v = *(const float4*)s;
  ushort4 o;
  o.x = f2bf(v.x); o.y = f2bf(v.y); o.z = f2bf(v.z); o.w = f2bf(v.w);
  *(ushort4*)d = o;
}
__global__ __launch_bounds__(256) void pack_all(
    const float* __restrict__ x, const float* __restrict__ h,
    const float* __restrict__ Wir, const float* __restrict__ Wiz,
    const float* __restrict__ Wih, const float* __restrict__ Whr,
    const float* __restrict__ Whz, const float* __restrict__ Whh,
    unsigned short* __restrict__ xh, unsigned short* __restrict__ Wrz,
    unsigned short* __restrict__ Wh_) {
  const int stride = gridDim.x * 256;
  for (int g = blockIdx.x * 256 + threadIdx.x; g < 11010048; g += stride) {
    if (g < 2097152) {            // x (8192x1024) -> xh[:, :1024]
      int r = g >> 8, c = (g & 255) << 2;
      cvt4(x + (long long)r * 1024 + c, xh + (long long)r * KC + c);
    } else if (g < 6291456) {     // h (8192x2048) -> xh[:, 1024:]
      int gg = g - 2097152; int r = gg >> 9, c = (gg & 511) << 2;
      cvt4(h + (long long)r * 2048 + c, xh + (long long)r * KC + IN_DIM + c);
    } else if (g < 6815744) {     // W_ir -> Wrz[0:2048, :1024]
      int gg = g - 6291456; int r = gg >> 8, c = (gg & 255) << 2;
      cvt4(Wir + (long long)r * 1024 + c, Wrz + (long long)r * KC + c);
    } else if (g < 7864320) {     // W_hr -> Wrz[0:2048, 1024:]
      int gg = g - 6815744; int r = gg >> 9, c = (gg & 511) << 2;
      cvt4(Whr + (long long)r * 2048 + c, Wrz + (long long)r * KC + IN_DIM + c);
    } else if (g < 8388608) {     // W_iz -> Wrz[2048:, :1024]
      int gg = g - 7864320; int r = gg >> 8, c = (gg & 255) << 2;
      cvt4(Wiz + (long long)r * 1024 + c, Wrz + (long long)(r + 2048) * KC + c);
    } else if (g < 9437184) {     // W_hz -> Wrz[2048:, 1024:]
      int gg = g - 8388608; int r = gg >> 9, c = (gg & 511) << 2;
      cvt4(Whz + (long long)r * 2048 + c, Wrz + (long long)(r + 2048) * KC + IN_DIM + c);
    } else if (g < 9961472) {     // W_ih -> Wh[:, :1024]
      int gg = g - 9437184; int r = gg >> 8, c = (gg & 255) << 2;
      cvt4(Wih + (long long)r * 1024 + c, Wh_ + (long long)r * KC + c);
    } else {                      // W_hh -> Wh[:, 1024:]
      int gg = g - 9961472; int r = gg >> 9, c = (gg & 511) << 2;
      cvt4(Whh + (long long)r * 2048 + c, Wh_ + (long long)r * KC + IN_DIM + c);
    }
  }
}

// ---------- 256x256 bf16 GEMM, BK=64, read-ahead pipelined 4-phase schedule ----------
#define SB0 __builtin_amdgcn_sched_barrier(0)
#define BAR __builtin_amdgcn_s_barrier()
#define VMC(n) asm volatile("s_waitcnt vmcnt(" #n ")" ::: "memory")
#define WLG(n) asm volatile("s_waitcnt lgkmcnt(" #n ")" ::: "memory")
#define PRIO1 __builtin_amdgcn_s_setprio(1)
#define PRIO0 __builtin_amdgcn_s_setprio(0)

#define STG(srcp, dstc) gload16((srcp), (unsigned short*)(dstc) + tid * 8)
#define STGHALF(srcb, o0, o1, dstc) do { STG((srcb) + (o0), (dstc)); STG((srcb) + (o1), (char*)(dstc) + 8192); } while (0)

// Read an A fragment set (4 M-frags x 2 k-slices = 8 ds_read_b128)
#define RD_A(dst, bufc, i0) do { _Pragma("unroll") for (int i_ = 0; i_ < 4; i_++) { \
    dst[i_][0] = *(const bf16x8*)((bufc) + aBase + ((i0) + i_) * 2048 + xs0);        \
    dst[i_][1] = *(const bf16x8*)((bufc) + aBase + ((i0) + i_) * 2048 + xs1); } } while (0)
// Read a B fragment pair (2 N-frags x 2 k-slices = 4 ds_read_b128)
#define RD_B(dst, bufc, j0) do { _Pragma("unroll") for (int j_ = 0; j_ < 2; j_++) { \
    dst[j_][0] = *(const bf16x8*)((bufc) + bBase + ((j0) + j_) * 2048 + xs0);        \
    dst[j_][1] = *(const bf16x8*)((bufc) + bBase + ((j0) + j_) * 2048 + xs1); } } while (0)

// One C-quadrant x K=64: 4i x 2j x 2k = 16 MFMA
#define MFMAQ(Aset, Bset, qm, qn) do { _Pragma("unroll") for (int i_ = 0; i_ < 4; i_++) \
    _Pragma("unroll") for (int j_ = 0; j_ < 2; j_++) {                                  \
      acc[(qm) * 4 + i_][(qn) * 2 + j_] = __builtin_amdgcn_mfma_f32_16x16x32_bf16(      \
          Aset[i_][0], Bset[j_][0], acc[(qm) * 4 + i_][(qn) * 2 + j_], 0, 0, 0);        \
      acc[(qm) * 4 + i_][(qn) * 2 + j_] = __builtin_amdgcn_mfma_f32_16x16x32_bf16(      \
          Aset[i_][1], Bset[j_][1], acc[(qm) * 4 + i_][(qn) * 2 + j_], 0, 0, 0); } } while (0)

#define ASRC(s) (((s) < splitT ? gA_lo : gA_hi) + (long long)(s) * 64)
#define BSRC(s) (gB_ + (long long)(s) * 64)

// Per-tile 4-phase body. AC/BC = current tile's buffers, AN/BN = next tile's.
// Reads run one phase ahead of their consuming MFMA; counted lgkmcnt only.
#define TILE_BODY(T, AC, AN, BC, BN) do {                                   \
  const int u1 = ((T) + 1 > LASTT) ? LASTT : (T) + 1;                        \
  const int u2 = ((T) + 2 > LASTT) ? LASTT : (T) + 2;                        \
  /* q0: MFMA(0,0) on A0_,Bx ; read B[2:3] of T ; stage B(T+1)h1 */          \
  RD_B(By, BC, 2);                                                           \
  STGHALF(BSRC(u1), OFF_H1Q0, OFF_H1Q1, (BN) + 16384);                       \
  SB0; WLG(4); SB0;                                                          \
  PRIO1; MFMAQ(A0_, Bx, 0, 0); PRIO0;                                        \
  /* q1: MFMA(0,1) on A0_,By ; read A[4:7] of T ; BAR certifies B(T) read */ \
  SB0;                                                                       \
  RD_A(A1_, AC, 4);                                                          \
  SB0; WLG(8); SB0; BAR;                                                     \
  STGHALF(BSRC(u2), OFF_H0Q0, OFF_H0Q1, (BC));                               \
  SB0;                                                                       \
  PRIO1; MFMAQ(A0_, By, 0, 1); PRIO0;                                        \
  /* q2: MFMA(1,0) on A1_,Bx ; BAR certifies A(T) read */                    \
  SB0; WLG(0); SB0; BAR;                                                     \
  STGHALF(ASRC(u2), OFF_H0Q0, OFF_H0Q1, (AC));                               \
  SB0;                                                                       \
  PRIO1; MFMAQ(A1_, Bx, 1, 0); PRIO0;                                        \
  /* q3: MFMA(1,1) on A1_,By ; VMC4+BAR certifies tile T+1 landed; read it */\
  SB0; VMC(4); SB0; BAR;                                                     \
  RD_A(A0_, AN, 0);                                                          \
  RD_B(Bx, BN, 0);                                                           \
  STGHALF(ASRC(u2), OFF_H1Q0, OFF_H1Q1, (AC) + 16384);                       \
  SB0; WLG(12); SB0;                                                         \
  PRIO1; MFMAQ(A1_, By, 1, 1); PRIO0;                                        \
} while (0)

// MODE 0: n<H: a = sigmoid(v+b_r)*h_prev -> xa ; n>=H: z = sigmoid(v+b_z) -> zbuf
// MODE 1: h_tilde = tanh(v+b_h); out = (1-z)*h + z*h_tilde
template <int MODE>
__global__ __launch_bounds__(512) void gemm256(
    const unsigned short* __restrict__ Alo_,  // A source for k-tiles < splitT
    const unsigned short* __restrict__ Ahi_,  // A source for k-tiles >= splitT
    int splitT,
    const unsigned short* __restrict__ Wm,    // N x K bf16
    int NTILN,
    const float* __restrict__ bias0,
    const float* __restrict__ bias1,
    const float* __restrict__ h_prev,
    unsigned short* __restrict__ xa,
    float* __restrict__ zbuf,
    float* __restrict__ out) {
  __shared__ char ldsA[2 * 32768];  // [buf][half 16KB = 128 rows x 128B]
  __shared__ char ldsB[2 * 32768];

  const int tid = threadIdx.x;
  const int lane = tid & 63;
  const int wave = tid >> 6;
  const int wm = wave >> 2;  // 0..1
  const int wn = wave & 3;   // 0..3

  // T1: XCD-aware block swizzle (grid %8 == 0)
  const int nwg = gridDim.x;
  const int cpx = nwg >> 3;
  const int bid = blockIdx.x;
  const int swz = (bid & 7) * cpx + (bid >> 3);
  const int bn = (swz % NTILN) * 256;
  const int bm = (swz / NTILN) * 256;

  // ---- read-side thread constants (chunk-XOR swizzle p = c ^ (row&7)) ----
  const int fr = lane & 15;
  const int cq = lane >> 4;
  const int xs0 = ((cq ^ (fr & 7)) << 4);
  const int xs1 = (((4 | cq) ^ (fr & 7)) << 4);
  const int aBase = wm * 16384 + fr * 128;
  const int bBase = wn * 8192 + fr * 128;

  // ---- stage-side constants (linear LDS dest, inverse-swizzled source) ----
  const int srow = tid >> 3;
  const int schk = (tid & 7) ^ ((tid >> 3) & 7);
  const unsigned short* gA_lo = Alo_ + (long long)(bm + srow) * KC + schk * 8;
  const unsigned short* gA_hi = Ahi_ + (long long)(bm + srow) * KC + schk * 8;
  const unsigned short* gB_   = Wm  + (long long)(bn + srow) * KC + schk * 8;

  char* const Ae = &ldsA[0];
  char* const Ao = &ldsA[32768];
  char* const Be = &ldsB[0];
  char* const Bo = &ldsB[32768];

  f32x4 acc[8][4] = {};
  bf16x8 A0_[4][2], A1_[4][2], Bx[2][2], By[2][2];

  // ---- prologue: tile0 full (8 gl) + tile1 A-h0,B-h0,A-h1 (6 gl) ----
  STGHALF(ASRC(0), OFF_H0Q0, OFF_H0Q1, Ae);
  STGHALF(ASRC(0), OFF_H1Q0, OFF_H1Q1, Ae + 16384);
  STGHALF(BSRC(0), OFF_H0Q0, OFF_H0Q1, Be);
  STGHALF(BSRC(0), OFF_H1Q0, OFF_H1Q1, Be + 16384);
  STGHALF(ASRC(1), OFF_H0Q0, OFF_H0Q1, Ao);
  STGHALF(BSRC(1), OFF_H0Q0, OFF_H0Q1, Bo);
  STGHALF(ASRC(1), OFF_H1Q0, OFF_H1Q1, Ao + 16384);
  VMC(6);  // tile0's 8 landed; tile1's 6 in flight
  BAR;
  // pre-loop reads: A0_[0:3], Bx[0:1] of tile 0
  RD_A(A0_, Ae, 0);
  RD_B(Bx, Be, 0);
  SB0;

  for (int it = 0; it < NTILES / 2; ++it) {
    const int t0 = it * 2;
    TILE_BODY(t0, Ae, Ao, Be, Bo);
    TILE_BODY(t0 + 1, Ao, Ae, Bo, Be);
  }

  // ---- fused epilogue. C/D layout: col = lane&15, row = (lane>>4)*4 + reg ----
  const int cr = (lane >> 4) << 2;
  const int cc = lane & 15;
#pragma unroll
  for (int i = 0; i < 8; i++) {
#pragma unroll
    for (int j = 0; j < 4; j++) {
#pragma unroll
      for (int e = 0; e < 4; e++) {
        const int m = bm + wm * 128 + i * 16 + cr + e;
        const int n = bn + wn * 64 + j * 16 + cc;
        const float v = acc[i][j][e];
        if (MODE == 0) {
          if (n < H_DIM) {
            const float g = sigmoidf_(v + bias0[n]);
            const float a = g * h_prev[(long long)m * H_DIM + n];
            xa[(long long)m * KC + IN_DIM + n] = f2bf(a);
          } else {
            const int nz = n - H_DIM;
            const float g = sigmoidf_(v + bias1[nz]);
            zbuf[(long long)m * H_DIM + nz] = g;
          }
        } else {
          const float ht = tanhf_(v + bias0[n]);
          const long long off = (long long)m * H_DIM + n;
          const float z = zbuf[off];
          const float h = h_prev[off];
          out[off] = (1.f - z) * h + z * ht;
        }
      }
    }
  }
}

extern "C" void kernel_launch(void* const* d_in, const int* in_sizes, int n_in,
                              void* d_out, int out_size, void* d_ws, size_t ws_size,
                              hipStream_t stream) {
  const float* x    = (const float*)d_in[0];   // (B, IN)
  const float* h    = (const float*)d_in[1];   // (B, H)
  const float* W_ir = (const float*)d_in[2];   // (H, IN)
  const float* W_iz = (const float*)d_in[3];
  const float* W_ih = (const float*)d_in[4];
  const float* W_hr = (const float*)d_in[5];   // (H, H)
  const float* W_hz = (const float*)d_in[6];
  const float* W_hh = (const float*)d_in[7];
  const float* b_r  = (const float*)d_in[8];
  const float* b_z  = (const float*)d_in[9];
  const float* b_h  = (const float*)d_in[10];
  float* out = (float*)d_out;

  // workspace layout (bytes)
  char* ws = (char*)d_ws;
  unsigned short* xh  = (unsigned short*)(ws);                      // B x KC bf16
  unsigned short* xa  = (unsigned short*)(ws + 50331648LL);         // B x KC bf16 (k>=IN region used)
  unsigned short* Wrz = (unsigned short*)(ws + 100663296LL);        // 2H x KC bf16
  unsigned short* Wh  = (unsigned short*)(ws + 125829120LL);        // H x KC bf16
  // z is stashed fp32 in d_out between GEMM_A and GEMM_B.

  // ---- single fused pack ----
  pack_all<<<4096, 256, 0, stream>>>(x, h, W_ir, W_iz, W_ih, W_hr, W_hz, W_hh,
                                     xh, Wrz, Wh);

  // ---- GEMM_A: [x|h] @ Wrz^T -> r,z gates; writes a into xa, z into d_out ----
  {
    const int ntiln = 4096 / 256;                 // 16
    dim3 grid((B_DIM / 256) * ntiln);             // 512 blocks (%8==0)
    gemm256<0><<<grid, 512, 0, stream>>>(xh, xh, 0, Wrz, ntiln,
                                         b_r, b_z, h, xa, out, nullptr);
  }
  // ---- GEMM_B: [x (xh) | a (xa)] @ Wh^T -> h_tilde; final h_t ----
  {
    const int ntiln = 2048 / 256;                 // 8
    dim3 grid((B_DIM / 256) * ntiln);             // 256 blocks (%8==0)
    gemm256<1><<<grid, 512, 0, stream>>>(xh, xa, IN_DIM / 64, Wh, ntiln,
                                         b_h, nullptr, h, nullptr, out, out);
  }
}

// Round 6
// 437.056 us; speedup vs baseline: 1.0802x; 1.0802x over previous
//
#include <hip/hip_runtime.h>
#include <cstdint>

// Problem dims (compile-time)
#define B_DIM 8192
#define IN_DIM 1024
#define H_DIM 2048
#define KC 3072      // IN + H (both GEMMs have K = 3072)
#define NTILES 48    // KC / 64
// Stage source offsets for (half h, round q): (h*128 + q*64) * KC elems
#define OFF_H0Q0 0
#define OFF_H0Q1 196608
#define OFF_H1Q0 393216
#define OFF_H1Q1 589824

typedef __attribute__((ext_vector_type(8))) __bf16 bf16x8;
typedef __attribute__((ext_vector_type(4))) float f32x4;

// ---------- helpers ----------
__device__ __forceinline__ unsigned short f2bf(float f) {
  unsigned int u = __float_as_uint(f);
  unsigned int r = (u + 0x7fffu + ((u >> 16) & 1u)) >> 16;
  return (unsigned short)r;
}
__device__ __forceinline__ float sigmoidf_(float x) {
  return 1.0f / (1.0f + __expf(-x));
}
__device__ __forceinline__ float tanhf_(float x) {
  float xc = fminf(fmaxf(x, -15.f), 15.f);
  float t = __expf(2.f * xc);
  return (t - 1.f) / (t + 1.f);
}
__device__ __forceinline__ void gload16(const unsigned short* g, unsigned short* l) {
  __builtin_amdgcn_global_load_lds(
      (const __attribute__((address_space(1))) unsigned int*)(g),
      (__attribute__((address_space(3))) unsigned int*)(l),
      16, 0, 0);
}

// ---------- fused pack: all fp32->bf16 conversions in one launch ----------
__device__ __forceinline__ void cvt4(const float* s, unsigned short* d) {
  const float4 v = *(const float4*)s;
  ushort4 o;
  o.x = f2bf(v.x); o.y = f2bf(v.y); o.z = f2bf(v.z); o.w = f2bf(v.w);
  *(ushort4*)d = o;
}
__global__ __launch_bounds__(256) void pack_all(
    const float* __restrict__ x, const float* __restrict__ h,
    const float* __restrict__ Wir, const float* __restrict__ Wiz,
    const float* __restrict__ Wih, const float* __restrict__ Whr,
    const float* __restrict__ Whz, const float* __restrict__ Whh,
    unsigned short* __restrict__ xh, unsigned short* __restrict__ Wrz,
    unsigned short* __restrict__ Wh_) {
  const int stride = gridDim.x * 256;
  for (int g = blockIdx.x * 256 + threadIdx.x; g < 11010048; g += stride) {
    if (g < 2097152) {            // x (8192x1024) -> xh[:, :1024]
      int r = g >> 8, c = (g & 255) << 2;
      cvt4(x + (long long)r * 1024 + c, xh + (long long)r * KC + c);
    } else if (g < 6291456) {     // h (8192x2048) -> xh[:, 1024:]
      int gg = g - 2097152; int r = gg >> 9, c = (gg & 511) << 2;
      cvt4(h + (long long)r * 2048 + c, xh + (long long)r * KC + IN_DIM + c);
    } else if (g < 6815744) {     // W_ir -> Wrz[0:2048, :1024]
      int gg = g - 6291456; int r = gg >> 8, c = (gg & 255) << 2;
      cvt4(Wir + (long long)r * 1024 + c, Wrz + (long long)r * KC + c);
    } else if (g < 7864320) {     // W_hr -> Wrz[0:2048, 1024:]
      int gg = g - 6815744; int r = gg >> 9, c = (gg & 511) << 2;
      cvt4(Whr + (long long)r * 2048 + c, Wrz + (long long)r * KC + IN_DIM + c);
    } else if (g < 8388608) {     // W_iz -> Wrz[2048:, :1024]
      int gg = g - 7864320; int r = gg >> 8, c = (gg & 255) << 2;
      cvt4(Wiz + (long long)r * 1024 + c, Wrz + (long long)(r + 2048) * KC + c);
    } else if (g < 9437184) {     // W_hz -> Wrz[2048:, 1024:]
      int gg = g - 8388608; int r = gg >> 9, c = (gg & 511) << 2;
      cvt4(Whz + (long long)r * 2048 + c, Wrz + (long long)(r + 2048) * KC + IN_DIM + c);
    } else if (g < 9961472) {     // W_ih -> Wh[:, :1024]
      int gg = g - 9437184; int r = gg >> 8, c = (gg & 255) << 2;
      cvt4(Wih + (long long)r * 1024 + c, Wh_ + (long long)r * KC + c);
    } else {                      // W_hh -> Wh[:, 1024:]
      int gg = g - 9961472; int r = gg >> 9, c = (gg & 511) << 2;
      cvt4(Whh + (long long)r * 2048 + c, Wh_ + (long long)r * KC + IN_DIM + c);
    }
  }
}

// ---------- 256x256 bf16 GEMM, BK=64, m201 8-phase template (no sched_barrier pins) ----------
#define BAR __builtin_amdgcn_s_barrier()
#define VMC4 asm volatile("s_waitcnt vmcnt(4)" ::: "memory")
#define LGK0 asm volatile("s_waitcnt lgkmcnt(0)" ::: "memory")
#define LGK8 asm volatile("s_waitcnt lgkmcnt(8)" ::: "memory")
#define PRIO1 __builtin_amdgcn_s_setprio(1)
#define PRIO0 __builtin_amdgcn_s_setprio(0)

#define STG(srcp, dstc) gload16((srcp), (unsigned short*)(dstc) + tid * 8)
#define STGHALF(srcb, o0, o1, dstc) do { STG((srcb) + (o0), (dstc)); STG((srcb) + (o1), (char*)(dstc) + 8192); } while (0)

#define RDA4(i0, bufc) do { _Pragma("unroll") for (int i_ = 0; i_ < 4; i_++) { \
    Aq[i_][0] = *(const bf16x8*)((bufc) + aBase + (i0 + i_) * 2048 + xs0);      \
    Aq[i_][1] = *(const bf16x8*)((bufc) + aBase + (i0 + i_) * 2048 + xs1); } } while (0)
#define RDB2(j0, bufc) do { _Pragma("unroll") for (int j_ = 0; j_ < 2; j_++) { \
    Bq[(j0) + j_][0] = *(const bf16x8*)((bufc) + bBase + ((j0) + j_) * 2048 + xs0); \
    Bq[(j0) + j_][1] = *(const bf16x8*)((bufc) + bBase + ((j0) + j_) * 2048 + xs1); } } while (0)

#define MFMAQ(qm, qn) do { _Pragma("unroll") for (int i_ = 0; i_ < 4; i_++)    \
    _Pragma("unroll") for (int j_ = 0; j_ < 2; j_++) {                          \
      acc[(qm) * 4 + i_][(qn) * 2 + j_] = __builtin_amdgcn_mfma_f32_16x16x32_bf16( \
          Aq[i_][0], Bq[(qn) * 2 + j_][0], acc[(qm) * 4 + i_][(qn) * 2 + j_], 0, 0, 0); \
      acc[(qm) * 4 + i_][(qn) * 2 + j_] = __builtin_amdgcn_mfma_f32_16x16x32_bf16( \
          Aq[i_][1], Bq[(qn) * 2 + j_][1], acc[(qm) * 4 + i_][(qn) * 2 + j_], 0, 0, 0); } } while (0)

// MODE 0: n<H: a = sigmoid(v+b_r)*h_prev -> xa ; n>=H: z = sigmoid(v+b_z) -> zbuf
// MODE 1: h_tilde = tanh(v+b_h); out = (1-z)*h + z*h_tilde
template <int MODE>
__global__ __launch_bounds__(512) void gemm256(
    const unsigned short* __restrict__ Alo_,  // A source for k-tiles < splitT
    const unsigned short* __restrict__ Ahi_,  // A source for k-tiles >= splitT
    int splitT,
    const unsigned short* __restrict__ Wm,    // N x K bf16
    int NTILN,
    const float* __restrict__ bias0,
    const float* __restrict__ bias1,
    const float* __restrict__ h_prev,
    unsigned short* __restrict__ xa,
    float* __restrict__ zbuf,
    float* __restrict__ out) {
  __shared__ char ldsA[2 * 32768];  // [buf][half 16KB][round 8KB]
  __shared__ char ldsB[2 * 32768];

  const int tid = threadIdx.x;
  const int lane = tid & 63;
  const int wave = tid >> 6;
  const int wm = wave >> 2;  // 0..1
  const int wn = wave & 3;   // 0..3

  // T1: XCD-aware block swizzle (grid %8 == 0)
  const int nwg = gridDim.x;
  const int cpx = nwg >> 3;
  const int bid = blockIdx.x;
  const int swz = (bid & 7) * cpx + (bid >> 3);
  const int bn = (swz % NTILN) * 256;
  const int bm = (swz / NTILN) * 256;

  // ---- read-side thread constants (chunk-XOR swizzle p = c ^ (row&7)) ----
  const int fr = lane & 15;
  const int cq = lane >> 4;                    // k-chunk within 32-k slice
  const int xs0 = ((cq ^ (fr & 7)) << 4);      // slice 0 chunk byte
  const int xs1 = (((4 | cq) ^ (fr & 7)) << 4);
  const int aBase = wm * 16384 + fr * 128;
  const int bBase = (wn >> 1) * 16384 + (wn & 1) * 8192 + fr * 128;

  // ---- stage-side constants (linear LDS dest, inverse-swizzled source) ----
  const int srow = tid >> 3;                   // row-in-round 0..63
  const int schk = (tid & 7) ^ ((tid >> 3) & 7);
  const unsigned short* gA_lo = Alo_ + (long long)(bm + srow) * KC + schk * 8;
  const unsigned short* gA_hi = Ahi_ + (long long)(bm + srow) * KC + schk * 8;
  const unsigned short* gB_   = Wm  + (long long)(bn + srow) * KC + schk * 8;
#define ASRC(s) (((s) < splitT ? gA_lo : gA_hi) + (long long)(s) * 64)

  char* const A0 = &ldsA[0];
  char* const A1 = &ldsA[32768];
  char* const B0 = &ldsB[0];
  char* const B1 = &ldsB[32768];

  f32x4 acc[8][4] = {};
  bf16x8 Aq[4][2], Bq[4][2];

  // ---- prologue: tile0 fully (8), tile1 B-h0 + A-h0 (4) ----
  STGHALF(ASRC(0), OFF_H0Q0, OFF_H0Q1, A0);
  STGHALF(ASRC(0), OFF_H1Q0, OFF_H1Q1, A0 + 16384);
  STGHALF(gB_, OFF_H0Q0, OFF_H0Q1, B0);
  STGHALF(gB_, OFF_H1Q0, OFF_H1Q1, B0 + 16384);
  STGHALF(gB_ + 64, OFF_H0Q0, OFF_H0Q1, B1);
  STGHALF(ASRC(1), OFF_H0Q0, OFF_H0Q1, A1);
  VMC4;
  BAR;

  for (int it = 0; it < NTILES / 2; ++it) {
    const int t0 = it * 2;
    const int t1 = t0 + 1;
    int e2 = t0 + 2; if (e2 > NTILES - 1) e2 = NTILES - 1;
    int o2 = t0 + 3; if (o2 > NTILES - 1) o2 = NTILES - 1;
    const unsigned short* aT1 = ASRC(t1);
    const unsigned short* aE2 = ASRC(e2);
    const unsigned short* aO2 = ASRC(o2);
    const unsigned short* bE2 = gB_ + (long long)e2 * 64;
    const unsigned short* bO2 = gB_ + (long long)o2 * 64;

    // P1: Q(0,0) of even tile; stage A(t1,h1)
    RDA4(0, A0); RDB2(0, B0);
    STGHALF(aT1, OFF_H1Q0, OFF_H1Q1, A1 + 16384);
    LGK8; BAR; LGK0;
    PRIO1; MFMAQ(0, 0); PRIO0; BAR;
    // P2: Q(0,1); stage B(t1,h1)
    RDB2(2, B0);
    STGHALF(gB_ + (long long)t1 * 64, OFF_H1Q0, OFF_H1Q1, B1 + 16384);
    BAR; LGK0;
    PRIO1; MFMAQ(0, 1); PRIO0; BAR;
    // P3: Q(1,0); stage B(e2,h0)
    RDA4(4, A0);
    STGHALF(bE2, OFF_H0Q0, OFF_H0Q1, B0);
    BAR; LGK0;
    PRIO1; MFMAQ(1, 0); PRIO0; BAR;
    // P4: Q(1,1); stage A(e2,h0); counted vmcnt
    STGHALF(aE2, OFF_H0Q0, OFF_H0Q1, A0);
    VMC4; BAR; LGK0;
    PRIO1; MFMAQ(1, 1); PRIO0; BAR;
    // P5: Q(0,0) of odd tile; stage A(e2,h1)
    RDA4(0, A1); RDB2(0, B1);
    STGHALF(aE2, OFF_H1Q0, OFF_H1Q1, A0 + 16384);
    LGK8; BAR; LGK0;
    PRIO1; MFMAQ(0, 0); PRIO0; BAR;
    // P6: Q(0,1); stage B(e2,h1)
    RDB2(2, B1);
    STGHALF(bE2, OFF_H1Q0, OFF_H1Q1, B0 + 16384);
    BAR; LGK0;
    PRIO1; MFMAQ(0, 1); PRIO0; BAR;
    // P7: Q(1,0); stage B(o2,h0)
    RDA4(4, A1);
    STGHALF(bO2, OFF_H0Q0, OFF_H0Q1, B1);
    BAR; LGK0;
    PRIO1; MFMAQ(1, 0); PRIO0; BAR;
    // P8: Q(1,1); stage A(o2,h0); counted vmcnt
    STGHALF(aO2, OFF_H0Q0, OFF_H0Q1, A1);
    VMC4; BAR; LGK0;
    PRIO1; MFMAQ(1, 1); PRIO0; BAR;
  }

  // ---- fused epilogue. C/D layout: col = lane&15, row = (lane>>4)*4 + reg ----
  const int cr = (lane >> 4) << 2;
  const int cc = lane & 15;
#pragma unroll
  for (int i = 0; i < 8; i++) {
#pragma unroll
    for (int j = 0; j < 4; j++) {
#pragma unroll
      for (int e = 0; e < 4; e++) {
        const int m = bm + wm * 128 + i * 16 + cr + e;
        const int n = bn + wn * 64 + j * 16 + cc;
        const float v = acc[i][j][e];
        if (MODE == 0) {
          if (n < H_DIM) {
            const float g = sigmoidf_(v + bias0[n]);
            const float a = g * h_prev[(long long)m * H_DIM + n];
            xa[(long long)m * KC + IN_DIM + n] = f2bf(a);
          } else {
            const int nz = n - H_DIM;
            const float g = sigmoidf_(v + bias1[nz]);
            zbuf[(long long)m * H_DIM + nz] = g;
          }
        } else {
          const float ht = tanhf_(v + bias0[n]);
          const long long off = (long long)m * H_DIM + n;
          const float z = zbuf[off];
          const float h = h_prev[off];
          out[off] = (1.f - z) * h + z * ht;
        }
      }
    }
  }
}

extern "C" void kernel_launch(void* const* d_in, const int* in_sizes, int n_in,
                              void* d_out, int out_size, void* d_ws, size_t ws_size,
                              hipStream_t stream) {
  const float* x    = (const float*)d_in[0];   // (B, IN)
  const float* h    = (const float*)d_in[1];   // (B, H)
  const float* W_ir = (const float*)d_in[2];   // (H, IN)
  const float* W_iz = (const float*)d_in[3];
  const float* W_ih = (const float*)d_in[4];
  const float* W_hr = (const float*)d_in[5];   // (H, H)
  const float* W_hz = (const float*)d_in[6];
  const float* W_hh = (const float*)d_in[7];
  const float* b_r  = (const float*)d_in[8];
  const float* b_z  = (const float*)d_in[9];
  const float* b_h  = (const float*)d_in[10];
  float* out = (float*)d_out;

  // workspace layout (bytes)
  char* ws = (char*)d_ws;
  unsigned short* xh  = (unsigned short*)(ws);                      // B x KC bf16
  unsigned short* xa  = (unsigned short*)(ws + 50331648LL);         // B x KC bf16 (k>=IN region used)
  unsigned short* Wrz = (unsigned short*)(ws + 100663296LL);        // 2H x KC bf16
  unsigned short* Wh  = (unsigned short*)(ws + 125829120LL);        // H x KC bf16
  // z is stashed fp32 in d_out between GEMM_A and GEMM_B.

  // ---- single fused pack ----
  pack_all<<<4096, 256, 0, stream>>>(x, h, W_ir, W_iz, W_ih, W_hr, W_hz, W_hh,
                                     xh, Wrz, Wh);

  // ---- GEMM_A: [x|h] @ Wrz^T -> r,z gates; writes a into xa, z into d_out ----
  {
    const int ntiln = 4096 / 256;                 // 16
    dim3 grid((B_DIM / 256) * ntiln);             // 512 blocks (%8==0)
    gemm256<0><<<grid, 512, 0, stream>>>(xh, xh, 0, Wrz, ntiln,
                                         b_r, b_z, h, xa, out, nullptr);
  }
  // ---- GEMM_B: [x (xh) | a (xa)] @ Wh^T -> h_tilde; final h_t ----
  {
    const int ntiln = 2048 / 256;                 // 8
    dim3 grid((B_DIM / 256) * ntiln);             // 256 blocks (%8==0)
    gemm256<1><<<grid, 512, 0, stream>>>(xh, xa, IN_DIM / 64, Wh, ntiln,
                                         b_h, nullptr, h, nullptr, out, out);
  }
}